// Round 9
// baseline (50.254 us; speedup 1.0000x reference)
//
#include <hip/hip_runtime.h>

// Problem constants (from reference setup_inputs)
#define BB 4
#define LL 8192
#define DD 1024
#define MAXC (LL / 4)      // 2048
#define MAGIC 0x5A17C0DEu  // "scan done" flag value (re-published every call)

typedef float f32x4 __attribute__((ext_vector_type(4)));
typedef int   i32x4 __attribute__((ext_vector_type(4)));

// ---------------------------------------------------------------------------
// Single fused kernel, 2048 blocks x 256 threads, 4 output rows per block.
//
// Blocks 0,512,1024,1536 scan their batch's mask (256 thr x 32 bits:
// popc + wave shuffle scan + 4-wave LDS round), scatter take_idx/pad_mask +
// ws_tk/ws_nc, then __threadfence() + agent-scope release-store MAGIC.
//
// R7 lesson: ALL 523k threads spinning on 4 cachelines serialized at one L2
// slice (438 us, VALUBusy 0.25%). Fix: ONLY thread 0 of each consumer block
// polls (2k spinners, relaxed + s_sleep backoff, one final acquire), then
// __syncthreads() broadcasts readiness to the block.
//
// Deadlock-free unconditionally: __launch_bounds__(256,8) => <=64 VGPR
// (R7 measured 20) => 8 blocks/CU x 256 CU = 2048 = entire grid co-resident,
// so producer blocks always make progress regardless of dispatch order.
//
// Gather path = R5 best config: 4 rows/block, cached loads (NT loads cost
// 2.4 us in R3), nontemporal stores (plain stores cost ~5 us in R6 by
// evicting the hs read set from L2).
// ---------------------------------------------------------------------------
__global__ __launch_bounds__(256, 8) void chunk_fused_kernel(
    const float* __restrict__ hs,        // [BB][LL][DD]
    const int*   __restrict__ mask,      // [BB][LL] 0/1
    int*          __restrict__ ws_tk,    // ws: [BB][MAXC]
    int*          __restrict__ ws_nc,    // ws: [BB]
    unsigned int* __restrict__ ws_flag,  // ws: [BB]
    float* __restrict__ out_chunk,       // [BB][MAXC][DD]
    float* __restrict__ out_pad,         // [BB][MAXC]
    float* __restrict__ out_tk)          // [BB][MAXC]
{
    const int t   = threadIdx.x;
    const int blk = blockIdx.x;           // 0..2047
    const int b   = blk >> 9;             // 512 blocks per batch
    const int r0  = (blk & 511) * 4;      // base output rank in batch

    if ((blk & 511) == 0) {
        // ---- producer: scan batch b (validated in R7, absmax 0) ----
        const int* m = mask + (size_t)b * LL;
        const i32x4* m4 = reinterpret_cast<const i32x4*>(m + t * 32);
        unsigned int bits = 0;
#pragma unroll
        for (int j = 0; j < 8; ++j) {
            i32x4 v = m4[j];
            bits |= (unsigned int)(v.x & 1) << (4 * j + 0);
            bits |= (unsigned int)(v.y & 1) << (4 * j + 1);
            bits |= (unsigned int)(v.z & 1) << (4 * j + 2);
            bits |= (unsigned int)(v.w & 1) << (4 * j + 3);
        }
        const int s = __popc(bits);

        const int lane = t & 63;
        const int wid  = t >> 6;          // 4 waves
        int inc = s;
#pragma unroll
        for (int off = 1; off < 64; off <<= 1) {
            int n = __shfl_up(inc, off, 64);
            if (lane >= off) inc += n;
        }
        __shared__ int wsum[4];
        if (lane == 63) wsum[wid] = inc;
        __syncthreads();

        int total = 0, wpre = 0;
#pragma unroll
        for (int w = 0; w < 4; ++w) {
            int x = wsum[w];
            total += x;
            wpre += (w < wid) ? x : 0;
        }
        const int P  = wpre + inc - s;    // boundaries before token t*32
        const int nc = (total < MAXC) ? total : MAXC;

        // Scatter ranks: boundary tokens in index order, then non-boundary.
        int pb = P;
        int nb = t * 32 - P;
        for (int j = 0; j < 32; ++j) {
            const int i   = t * 32 + j;
            const int bit = (bits >> j) & 1;
            const int r   = bit ? pb : (total + nb);
            pb += bit;
            nb += 1 - bit;
            if (r < MAXC) {
                const int o = b * MAXC + r;
                ws_tk[o]   = i;
                out_tk[o]  = (float)i;    // exact: i < 2^24
                out_pad[o] = (r < nc) ? 1.0f : 0.0f;
            }
        }
        if (t == 0) ws_nc[b] = nc;
        __threadfence();                  // device-visible before flag
        __syncthreads();
        if (t == 0)
            __hip_atomic_store(&ws_flag[b], MAGIC, __ATOMIC_RELEASE,
                               __HIP_MEMORY_SCOPE_AGENT);
    } else {
        // ---- consumer: single-thread poll, block-wide broadcast ----
        if (t == 0) {
            while (__hip_atomic_load(&ws_flag[b], __ATOMIC_RELAXED,
                                     __HIP_MEMORY_SCOPE_AGENT) != MAGIC) {
                __builtin_amdgcn_s_sleep(32);
            }
            (void)__hip_atomic_load(&ws_flag[b], __ATOMIC_ACQUIRE,
                                    __HIP_MEMORY_SCOPE_AGENT);
        }
        __syncthreads();
    }

    // ---- common gather: 4 rows of 4 KB (R5 winning config) ----
    const int nc = ws_nc[b];
    f32x4 vals[4];
#pragma unroll
    for (int k = 0; k < 4; ++k) {
        const int rr = r0 + k;
        if (rr < nc) {
            const int i = ws_tk[b * MAXC + rr];
            const f32x4* src = reinterpret_cast<const f32x4*>(
                hs + ((size_t)b * LL + i) * DD);
            vals[k] = src[t];                         // cached load
        } else {
            vals[k] = (f32x4){0.f, 0.f, 0.f, 0.f};
        }
    }

    f32x4* o = reinterpret_cast<f32x4*>(out_chunk + ((size_t)b * MAXC + r0) * DD);
#pragma unroll
    for (int k = 0; k < 4; ++k) {
        __builtin_nontemporal_store(vals[k], &o[k * 256 + t]);
    }
}

extern "C" void kernel_launch(void* const* d_in, const int* in_sizes, int n_in,
                              void* d_out, int out_size, void* d_ws, size_t ws_size,
                              hipStream_t stream) {
    const float* hs   = (const float*)d_in[0];   // [4][8192][1024] f32
    const int*   mask = (const int*)d_in[1];     // [4][8192] int (bool 0/1)

    float* out = (float*)d_out;
    float* out_chunk = out;                          // [4][2048][1024]
    float* out_pad   = out + (size_t)BB * MAXC * DD; // [4][2048]
    float* out_tk    = out_pad + (size_t)BB * MAXC;  // [4][2048]

    int*          ws_tk   = (int*)d_ws;              // [4][2048]
    int*          ws_nc   = ws_tk + BB * MAXC;       // [4]
    unsigned int* ws_flag = (unsigned int*)(ws_nc + BB); // [4]

    chunk_fused_kernel<<<BB * MAXC / 4, 256, 0, stream>>>(
        hs, mask, ws_tk, ws_nc, ws_flag, out_chunk, out_pad, out_tk);
}

// Round 10
// 18.896 us; speedup vs baseline: 2.6595x; 2.6595x over previous
//
#include <hip/hip_runtime.h>

// Problem constants (from reference setup_inputs)
#define BB 4
#define LL 8192
#define DD 1024
#define MAXC (LL / 4)   // 2048

typedef float f32x4 __attribute__((ext_vector_type(4)));
typedef int   i32x4 __attribute__((ext_vector_type(4)));

// ---------------------------------------------------------------------------
// Kernel 1 (slim): per-batch boundary scan -> tk_int / nchunks ONLY.
// One block of 512 threads per batch, 16 mask elements per thread
// (4 independent i32x4 loads in flight: latency-bound phase wants MLP).
// The gather kernel writes out_tk/out_pad itself (validated in R8),
// cutting this kernel's scattered-store streams from 3 to 1.
// Semantics replicate: argsort(i + (~mask)*L)[:MAXC]
//   = boundary positions in index order, then non-boundary positions in
//     index order (all token_idx values distinct, so order is exact).
// ---------------------------------------------------------------------------
__global__ __launch_bounds__(512) void chunk_scan_kernel(
    const int* __restrict__ mask,     // [BB][LL] 0/1
    int*       __restrict__ tk_int,   // ws: [BB][MAXC]
    int*       __restrict__ nchunks)  // ws: [BB]
{
    const int b = blockIdx.x;
    const int t = threadIdx.x;
    constexpr int PER = LL / 512;     // 16

    const int* m = mask + (size_t)b * LL;
    const i32x4* m4 = reinterpret_cast<const i32x4*>(m + t * PER);
    i32x4 v0 = m4[0];
    i32x4 v1 = m4[1];
    i32x4 v2 = m4[2];
    i32x4 v3 = m4[3];
    int local[PER] = {v0.x, v0.y, v0.z, v0.w, v1.x, v1.y, v1.z, v1.w,
                      v2.x, v2.y, v2.z, v2.w, v3.x, v3.y, v3.z, v3.w};

    int s = 0;
#pragma unroll
    for (int j = 0; j < PER; ++j) s += local[j];

    // Wave-level inclusive scan of per-thread sums (wave = 64 lanes).
    const int lane = t & 63;
    const int wid  = t >> 6;          // 8 waves
    int inc = s;
#pragma unroll
    for (int off = 1; off < 64; off <<= 1) {
        int n = __shfl_up(inc, off, 64);
        if (lane >= off) inc += n;
    }

    __shared__ int wsum[8];
    if (lane == 63) wsum[wid] = inc;
    __syncthreads();

    int wpre = 0, total = 0;
#pragma unroll
    for (int w = 0; w < 8; ++w) {     // broadcast reads, no conflicts
        int x = wsum[w];
        total += x;
        wpre += (w < wid) ? x : 0;
    }
    const int excl = wpre + inc - s;              // exclusive prefix (block)
    const int nc   = (total < MAXC) ? total : MAXC;

    // Assign each position its sorted rank; scatter tk only.
    int pb = excl;                    // #boundary strictly before i
    const int base = t * PER;
#pragma unroll
    for (int j = 0; j < PER; ++j) {
        const int i = base + j;
        const int r = local[j] ? pb : (total + (i - pb));
        pb += local[j];
        if (r < MAXC) tk_int[b * MAXC + r] = i;
    }
    if (t == 0) nchunks[b] = nc;
}

// ---------------------------------------------------------------------------
// Kernel 2: gather rows — byte-identical structure to the R5 winner.
// 2048 blocks x 256 threads; each block copies FOUR consecutive output rows
// (4 x 4 KB). Cached loads (read set L3-resident across replays; NT loads
// cost +2.4 us in R3), nontemporal stores (plain stores cost ~+5 us in R6
// by evicting the hs read set from L2). Also emits this block's 4
// out_tk/out_pad entries (moved here from the scan kernel).
// ---------------------------------------------------------------------------
__global__ __launch_bounds__(256) void chunk_gather_kernel(
    const float* __restrict__ hs,       // [BB][LL][DD]
    const int*   __restrict__ tk_int,   // [BB][MAXC]
    const int*   __restrict__ nchunks,  // [BB]
    float*       __restrict__ out_chunk,// [BB][MAXC][DD]
    float*       __restrict__ out_pad,  // [BB][MAXC]
    float*       __restrict__ out_tk)   // [BB][MAXC]
{
    const int t    = threadIdx.x;
    const int row0 = blockIdx.x * 4;    // 4 rows per block, same batch
    const int b    = row0 >> 11;        // / MAXC (2048)
    const int nc   = nchunks[b];

    // Small per-row outputs (take_idx as float, pad_mask).
    if (t < 4) {
        const int row = row0 + t;       // global row = b*MAXC + r
        const int r   = row & (MAXC - 1);
        out_tk[row]  = (float)tk_int[row];   // exact: < 2^24
        out_pad[row] = (r < nc) ? 1.0f : 0.0f;
    }

    f32x4 vals[4];
#pragma unroll
    for (int k = 0; k < 4; ++k) {
        const int row = row0 + k;
        const int r   = row & (MAXC - 1);
        if (r < nc) {
            const int i = tk_int[row];
            const f32x4* src =
                reinterpret_cast<const f32x4*>(hs + ((size_t)b * LL + i) * DD);
            vals[k] = src[t];                       // cached load
        } else {
            vals[k] = (f32x4){0.f, 0.f, 0.f, 0.f};
        }
    }

    f32x4* o = reinterpret_cast<f32x4*>(out_chunk + (size_t)row0 * DD);
#pragma unroll
    for (int k = 0; k < 4; ++k) {
        __builtin_nontemporal_store(vals[k], &o[k * 256 + t]);
    }
}

extern "C" void kernel_launch(void* const* d_in, const int* in_sizes, int n_in,
                              void* d_out, int out_size, void* d_ws, size_t ws_size,
                              hipStream_t stream) {
    const float* hs   = (const float*)d_in[0];   // [4][8192][1024] f32
    const int*   mask = (const int*)d_in[1];     // [4][8192] int (bool 0/1)

    float* out = (float*)d_out;
    float* out_chunk = out;                          // [4][2048][1024]
    float* out_pad   = out + (size_t)BB * MAXC * DD; // [4][2048]
    float* out_tk    = out_pad + (size_t)BB * MAXC;  // [4][2048]

    int* tk_int  = (int*)d_ws;                       // [4][2048]
    int* nchunks = tk_int + BB * MAXC;               // [4]

    chunk_scan_kernel<<<BB, 512, 0, stream>>>(mask, tk_int, nchunks);
    chunk_gather_kernel<<<BB * MAXC / 4, 256, 0, stream>>>(hs, tk_int, nchunks,
                                                           out_chunk, out_pad,
                                                           out_tk);
}